// Round 10
// baseline (329.767 us; speedup 1.0000x reference)
//
#include <hip/hip_runtime.h>
#include <math.h>

#define D_MODEL 1024
#define NHEADS  16
#define HD      64
#define BSZ     4
#define LSEQ    1024
#define BH      64

typedef _Float16 f16;
typedef _Float16 f16x8 __attribute__((ext_vector_type(8)));
typedef _Float16 f16x4 __attribute__((ext_vector_type(4)));
typedef float    f32x4 __attribute__((ext_vector_type(4)));

typedef const __attribute__((address_space(1))) void* gp1_t;
typedef __attribute__((address_space(3))) void* lp3_t;

__device__ __forceinline__ void gload_lds16(const void* g, void* l) {
    __builtin_amdgcn_global_load_lds((gp1_t)g, (lp3_t)l, 16, 0, 0);
}

// ---------------- weights cvt (4x) + lambda scalars folded in ----------------
__global__ __launch_bounds__(256) void cvt4_kernel(
    const float* __restrict__ s0, const float* __restrict__ s1,
    const float* __restrict__ s2, const float* __restrict__ s3,
    f16* __restrict__ d0, f16* __restrict__ d1, f16* __restrict__ d2, f16* __restrict__ d3,
    const float* __restrict__ lq, const float* __restrict__ lk,
    const float* __restrict__ lv, float* __restrict__ lam) {
    int which = blockIdx.y;
    const float* src = which == 0 ? s0 : which == 1 ? s1 : which == 2 ? s2 : s3;
    f16* dst = which == 0 ? d0 : which == 1 ? d1 : which == 2 ? d2 : d3;
    int i = blockIdx.x * blockDim.x + threadIdx.x;
    if (i < 131072) {
        float4 a = *(const float4*)(src + (size_t)i * 8);
        float4 b = *(const float4*)(src + (size_t)i * 8 + 4);
        f16x8 h;
        h[0]=(f16)a.x; h[1]=(f16)a.y; h[2]=(f16)a.z; h[3]=(f16)a.w;
        h[4]=(f16)b.x; h[5]=(f16)b.y; h[6]=(f16)b.z; h[7]=(f16)b.w;
        *(f16x8*)(dst + (size_t)i * 8) = h;
    }
    if (blockIdx.x == 0 && blockIdx.y == 0 && threadIdx.x < 64) {
        int t = threadIdx.x;
        float pc = lk[t] * lv[t];
        float ps = lq[t] * lk[t];
#pragma unroll
        for (int o = 32; o > 0; o >>= 1) {
            pc += __shfl_down(pc, o, 64);
            ps += __shfl_down(ps, o, 64);
        }
        if (t == 0) {
            float lamC = expf(pc), lamS = expf(ps);
            lam[0] = lamC; lam[1] = lamS;
            lam[2] = lamC / lamS;        // alpha: pre-scales Q
            lam[3] = 0.125f * lamS;      // gamma: post-scales MFMA scores
        }
    }
}

// ---------------- merged QKV projection: Y = X @ W^T + bias (f16 MFMA, dbuf) ----------------
// z=0: Qs (head-split f16, *alpha)   z=1: Kh   z=2: Vh + Vt (transposed copy)
__global__ __launch_bounds__(256, 2) void gemm_qkv_kernel(
    const float* __restrict__ q, const float* __restrict__ k, const float* __restrict__ v,
    const f16* __restrict__ Wq, const f16* __restrict__ Wk, const f16* __restrict__ Wv,
    const float* __restrict__ bq, const float* __restrict__ bk, const float* __restrict__ bv,
    const float* __restrict__ lam,
    f16* __restrict__ Qs, f16* __restrict__ Kh, f16* __restrict__ Vh, f16* __restrict__ Vt)
{
    __shared__ f16 At[2][128 * 64];   // pitch 128B, XOR-swizzled ((row&7)<<4)
    __shared__ f16 Bt[2][128 * 64];

    const int z = blockIdx.z;
    const float* X    = (z == 0) ? q  : (z == 1) ? k  : v;
    const f16*   W    = (z == 0) ? Wq : (z == 1) ? Wk : Wv;
    const float* bias = (z == 0) ? bq : (z == 1) ? bk : bv;

    const int t = threadIdx.x;
    const int lane = t & 63, w = t >> 6;
    const int g = lane >> 4, ln = lane & 15;
    const int wr = w >> 1, wc = w & 1;
    const int n0 = blockIdx.x * 128, m0 = blockIdx.y * 128;
    const int ar = t >> 1, ak = (t & 1) * 32;   // fp32 A staging: row, col-base

    f32x4 acc[4][4];
#pragma unroll
    for (int mi = 0; mi < 4; ++mi)
#pragma unroll
        for (int ni = 0; ni < 4; ++ni)
            acc[mi][ni] = (f32x4){0.f, 0.f, 0.f, 0.f};

    // prologue: stage tile 0
    {
        const float* src = X + (size_t)(m0 + ar) * 1024 + ak;
#pragma unroll
        for (int c = 0; c < 4; ++c) {
            float4 f0 = ((const float4*)src)[c * 2];
            float4 f1 = ((const float4*)src)[c * 2 + 1];
            f16x8 hv;
            hv[0]=(f16)f0.x; hv[1]=(f16)f0.y; hv[2]=(f16)f0.z; hv[3]=(f16)f0.w;
            hv[4]=(f16)f1.x; hv[5]=(f16)f1.y; hv[6]=(f16)f1.z; hv[7]=(f16)f1.w;
            int kb = (ak + c * 8) * 2;
            *(f16x8*)((char*)At[0] + ar * 128 + (kb ^ ((ar & 7) << 4))) = hv;
        }
#pragma unroll
        for (int i = 0; i < 4; ++i) {
            int o = t * 16 + i * 4096;
            int r = o >> 7, kb = (o & 127) ^ ((r & 7) << 4);
            gload_lds16(W + (size_t)(n0 + r) * 1024 + (kb >> 1), (char*)Bt[0] + o);
        }
    }
    __syncthreads();

    int cur = 0;
    for (int kt = 0; kt < 16; ++kt) {
        float4 pre[8];
        if (kt < 15) {
            const float* src = X + (size_t)(m0 + ar) * 1024 + (kt + 1) * 64 + ak;
#pragma unroll
            for (int c = 0; c < 8; ++c) pre[c] = ((const float4*)src)[c];
#pragma unroll
            for (int i = 0; i < 4; ++i) {
                int o = t * 16 + i * 4096;
                int r = o >> 7, kb = (o & 127) ^ ((r & 7) << 4);
                gload_lds16(W + (size_t)(n0 + r) * 1024 + (kt + 1) * 64 + (kb >> 1),
                            (char*)Bt[cur ^ 1] + o);
            }
        }
#pragma unroll
        for (int ks = 0; ks < 2; ++ks) {
            f16x8 af[4], bf[4];
#pragma unroll
            for (int mi = 0; mi < 4; ++mi) {
                int r = wr * 64 + mi * 16 + ln;
                af[mi] = *(const f16x8*)((const char*)At[cur] + r * 128 + ((ks * 64 + g * 16) ^ ((r & 7) << 4)));
            }
#pragma unroll
            for (int ni = 0; ni < 4; ++ni) {
                int r = wc * 64 + ni * 16 + ln;
                bf[ni] = *(const f16x8*)((const char*)Bt[cur] + r * 128 + ((ks * 64 + g * 16) ^ ((r & 7) << 4)));
            }
#pragma unroll
            for (int mi = 0; mi < 4; ++mi)
#pragma unroll
                for (int ni = 0; ni < 4; ++ni)
                    acc[mi][ni] = __builtin_amdgcn_mfma_f32_16x16x32_f16(af[mi], bf[ni], acc[mi][ni], 0, 0, 0);
        }
        if (kt < 15) {
#pragma unroll
            for (int c = 0; c < 4; ++c) {
                float4 f0 = pre[c * 2], f1 = pre[c * 2 + 1];
                f16x8 hv;
                hv[0]=(f16)f0.x; hv[1]=(f16)f0.y; hv[2]=(f16)f0.z; hv[3]=(f16)f0.w;
                hv[4]=(f16)f1.x; hv[5]=(f16)f1.y; hv[6]=(f16)f1.z; hv[7]=(f16)f1.w;
                int kb = (ak + c * 8) * 2;
                *(f16x8*)((char*)At[cur ^ 1] + ar * 128 + (kb ^ ((ar & 7) << 4))) = hv;
            }
        }
        __syncthreads();
        cur ^= 1;
    }

    const float alpha = (z == 0) ? lam[2] : 1.0f;
    f16* Y = (z == 0) ? Qs : (z == 1) ? Kh : Vh;
#pragma unroll
    for (int mi = 0; mi < 4; ++mi) {
#pragma unroll
        for (int ni = 0; ni < 4; ++ni) {
            int n = n0 + wc * 64 + ni * 16 + ln;
            int h = n >> 6, d = n & 63;
            float bn = bias[n];
            int mrow0 = m0 + wr * 64 + mi * 16 + 4 * g;
            int b = mrow0 >> 10, l0 = mrow0 & 1023;
            f16x4 tv;
#pragma unroll
            for (int qq = 0; qq < 4; ++qq) {
                float val = (acc[mi][ni][qq] + bn) * alpha;
                f16 hq = (f16)val;
                tv[qq] = hq;
                Y[(((size_t)(b * NHEADS + h)) * LSEQ + l0 + qq) * HD + d] = hq;
            }
            if (z == 2)
                *(f16x4*)(Vt + ((size_t)(b * NHEADS + h) * HD + d) * LSEQ + l0) = tv;
        }
    }
}

// ---------------- AO GEMM: out = AO @ Wo^T + bo (f16 A, fp32 out, dbuf) ----------------
__global__ __launch_bounds__(256, 2) void gemm_ao_kernel(
    const f16* __restrict__ A16, const f16* __restrict__ W16,
    const float* __restrict__ bias, float* __restrict__ out)
{
    __shared__ f16 At[2][128 * 64];
    __shared__ f16 Bt[2][128 * 64];

    const int t = threadIdx.x;
    const int lane = t & 63, w = t >> 6;
    const int g = lane >> 4, ln = lane & 15;
    const int wr = w >> 1, wc = w & 1;
    const int n0 = blockIdx.x * 128, m0 = blockIdx.y * 128;

    f32x4 acc[4][4];
#pragma unroll
    for (int mi = 0; mi < 4; ++mi)
#pragma unroll
        for (int ni = 0; ni < 4; ++ni)
            acc[mi][ni] = (f32x4){0.f, 0.f, 0.f, 0.f};

#pragma unroll
    for (int i = 0; i < 4; ++i) {
        int o = t * 16 + i * 4096;
        int r = o >> 7, kb = (o & 127) ^ ((r & 7) << 4);
        gload_lds16(A16 + (size_t)(m0 + r) * 1024 + (kb >> 1), (char*)At[0] + o);
        gload_lds16(W16 + (size_t)(n0 + r) * 1024 + (kb >> 1), (char*)Bt[0] + o);
    }
    __syncthreads();

    int cur = 0;
    for (int kt = 0; kt < 16; ++kt) {
        if (kt < 15) {
#pragma unroll
            for (int i = 0; i < 4; ++i) {
                int o = t * 16 + i * 4096;
                int r = o >> 7, kb = (o & 127) ^ ((r & 7) << 4);
                gload_lds16(A16 + (size_t)(m0 + r) * 1024 + (kt + 1) * 64 + (kb >> 1), (char*)At[cur ^ 1] + o);
                gload_lds16(W16 + (size_t)(n0 + r) * 1024 + (kt + 1) * 64 + (kb >> 1), (char*)Bt[cur ^ 1] + o);
            }
        }
#pragma unroll
        for (int ks = 0; ks < 2; ++ks) {
            f16x8 af[4], bf[4];
#pragma unroll
            for (int mi = 0; mi < 4; ++mi) {
                int r = wr * 64 + mi * 16 + ln;
                af[mi] = *(const f16x8*)((const char*)At[cur] + r * 128 + ((ks * 64 + g * 16) ^ ((r & 7) << 4)));
            }
#pragma unroll
            for (int ni = 0; ni < 4; ++ni) {
                int r = wc * 64 + ni * 16 + ln;
                bf[ni] = *(const f16x8*)((const char*)Bt[cur] + r * 128 + ((ks * 64 + g * 16) ^ ((r & 7) << 4)));
            }
#pragma unroll
            for (int mi = 0; mi < 4; ++mi)
#pragma unroll
                for (int ni = 0; ni < 4; ++ni)
                    acc[mi][ni] = __builtin_amdgcn_mfma_f32_16x16x32_f16(af[mi], bf[ni], acc[mi][ni], 0, 0, 0);
        }
        __syncthreads();
        cur ^= 1;
    }

#pragma unroll
    for (int mi = 0; mi < 4; ++mi)
#pragma unroll
        for (int ni = 0; ni < 4; ++ni) {
            int n = n0 + wc * 64 + ni * 16 + ln;
            float bn = bias[n];
#pragma unroll
            for (int qq = 0; qq < 4; ++qq) {
                int m = m0 + wr * 64 + mi * 16 + 4 * g + qq;
                out[(size_t)m * 1024 + n] = acc[mi][ni][qq] + bn;
            }
        }
}

// ---------------- single-pass fused attention, lane-coalesced PLAIN-store streaming ----------------
// Identical to round 9 except phase 2b uses plain (L2 write-combining) stores
// instead of nontemporal -- A/B test of the nt-store path.
__global__ __launch_bounds__(512, 4) void attn_kernel(
    const f16* __restrict__ Qs, const f16* __restrict__ Kh, const f16* __restrict__ Vh,
    const f16* __restrict__ Vt, const float* __restrict__ lam,
    float* __restrict__ attnW, f16* __restrict__ AO)
{
    __shared__ __align__(16) f16 WsAll[16][2048];   // 16 tiles x (32 rows x 128B), XOR-swizzled
    __shared__ float rsum[4][2][16];                // [ci][ri][ln]

    const int t = threadIdx.x;
    const int lane = t & 63, w = t >> 6;
    const int g = lane >> 4, ln = lane & 15;
    const int ci = w & 3, ri = w >> 2;          // phase-1 wave role

    const int bid = blockIdx.x;                 // 0..2047
    const int wg = (bid & 7) * 256 + (bid >> 3);// XCD-contiguous swizzle (8 XCDs)
    const int bh = wg >> 5, rb = wg & 31;
    const size_t hbase = (size_t)bh * LSEQ * HD;
    const float gamma = lam[3];

    if (t < 128) ((float*)rsum)[t] = 0.f;

    // Q-side B-frags: row = rb*32 + ri*16 + ln, [alpha*Q | K] along k
    f16x8 qf[4];
    {
        const int qrow = rb * 32 + ri * 16 + ln;
        const f16* qp = Qs + hbase + (size_t)qrow * HD;
        const f16* kp = Kh + hbase + (size_t)qrow * HD;
        qf[0] = *(const f16x8*)(qp + g * 8);
        qf[1] = *(const f16x8*)(qp + 32 + g * 8);
        qf[2] = *(const f16x8*)(kp + g * 8);
        qf[3] = *(const f16x8*)(kp + 32 + g * 8);
    }
    __syncthreads();   // rsum init fence

    // ---------- phase 1: scores + exp + row sums (no barriers) ----------
    float lsum = 0.f;
    f16x4 sregh[16];
#pragma unroll
    for (int tt = 0; tt < 16; ++tt) {
        const f16* kr = Kh + hbase + (size_t)(tt * 64 + ci * 16 + ln) * HD;
        const f16* vr = Vh + hbase + (size_t)(tt * 64 + ci * 16 + ln) * HD;
        f16x8 a0 = *(const f16x8*)(kr + g * 8);
        f16x8 a1 = *(const f16x8*)(kr + 32 + g * 8);
        f16x8 a2 = *(const f16x8*)(vr + g * 8);
        f16x8 a3 = *(const f16x8*)(vr + 32 + g * 8);
        f32x4 acc = (f32x4){0.f, 0.f, 0.f, 0.f};
        acc = __builtin_amdgcn_mfma_f32_16x16x32_f16(a0, qf[0], acc, 0, 0, 0);
        acc = __builtin_amdgcn_mfma_f32_16x16x32_f16(a1, qf[1], acc, 0, 0, 0);
        acc = __builtin_amdgcn_mfma_f32_16x16x32_f16(a2, qf[2], acc, 0, 0, 0);
        acc = __builtin_amdgcn_mfma_f32_16x16x32_f16(a3, qf[3], acc, 0, 0, 0);
        float e0 = __expf(acc[0] * gamma);
        float e1 = __expf(acc[1] * gamma);
        float e2 = __expf(acc[2] * gamma);
        float e3 = __expf(acc[3] * gamma);
        lsum += (e0 + e1) + (e2 + e3);
        f16x4 eh;
        eh[0] = (f16)e0; eh[1] = (f16)e1; eh[2] = (f16)e2; eh[3] = (f16)e3;
        sregh[tt] = eh;
    }
    lsum += __shfl_xor(lsum, 16, 64);
    lsum += __shfl_xor(lsum, 32, 64);
    if (g == 0) rsum[ci][ri][ln] = lsum;
    __syncthreads();
    const float il = 1.0f / ((rsum[0][ri][ln] + rsum[1][ri][ln]) +
                             (rsum[2][ri][ln] + rsum[3][ri][ln]));

    // ---------- phase 2a: normalized f16 weights -> WsAll (no global stores) ----------
    const int r1 = ri * 16 + ln;                           // this wave's score row
    const int wsw = (32 * ci + 8 * g) ^ ((r1 & 7) << 4);   // Ws write byte offset in row
#pragma unroll
    for (int tt = 0; tt < 16; ++tt) {
        f16x4 eh = sregh[tt];
        f16x4 wh;
        wh[0] = (f16)((float)eh[0] * il);
        wh[1] = (f16)((float)eh[1] * il);
        wh[2] = (f16)((float)eh[2] * il);
        wh[3] = (f16)((float)eh[3] * il);
        *(f16x4*)((char*)WsAll[tt] + r1 * 128 + wsw) = wh;
    }
    __syncthreads();   // the ONE barrier: WsAll visible to all waves

    // ---------- phase 2b: lane-coalesced attnW stream (plain stores) ----------
    // Wave w owns rows 4w..4w+3. Per instruction: lane l covers float cols
    // qu*256 + l*4 .. +4 of one row -> 64 lanes x 16B = 1KB contiguous.
    {
#pragma unroll
        for (int rr = 0; rr < 4; ++rr) {
            const int row = w * 4 + rr;
            const int swz = row & 7;
            const int lds_off = row * 128 + ((((lane & 15) * 8)) ^ (swz << 4));
            float* gdst = attnW + ((size_t)bh * LSEQ + rb * 32 + row) * LSEQ + lane * 4;
#pragma unroll
            for (int qu = 0; qu < 4; ++qu) {
                const int s = qu * 4 + (lane >> 4);
                f16x4 hv = *(const f16x4*)((const char*)WsAll[s] + lds_off);
                f32x4 o;
                o[0] = (float)hv[0]; o[1] = (float)hv[1];
                o[2] = (float)hv[2]; o[3] = (float)hv[3];
                *(f32x4*)(gdst + qu * 256) = o;
            }
        }
    }

    // ---------- phase 2c: PV over WsAll (overlaps store drain) ----------
    const int dj = w & 3, rb2 = w >> 2;         // phase-2 wave role
    const int r2 = rb2 * 16 + ln;               // pa row
    const int dd = dj * 16 + ln;                // Vt row
    const f16* vtrow = Vt + (size_t)bh * HD * LSEQ + (size_t)dd * LSEQ;
    const int psw0 = (16 * g) ^ ((r2 & 7) << 4);           // pa ks=0 byte offset
    const int psw1 = (64 + 16 * g) ^ ((r2 & 7) << 4);      // pa ks=1
    f32x4 oacc = (f32x4){0.f, 0.f, 0.f, 0.f};

#pragma unroll
    for (int tt = 0; tt < 16; ++tt) {
        f16x8 vb0 = *(const f16x8*)(vtrow + tt * 64 + g * 8);
        f16x8 vb1 = *(const f16x8*)(vtrow + tt * 64 + 32 + g * 8);
        f16x8 pa0 = *(const f16x8*)((const char*)WsAll[tt] + r2 * 128 + psw0);
        f16x8 pa1 = *(const f16x8*)((const char*)WsAll[tt] + r2 * 128 + psw1);
        oacc = __builtin_amdgcn_mfma_f32_16x16x32_f16(pa0, vb0, oacc, 0, 0, 0);
        oacc = __builtin_amdgcn_mfma_f32_16x16x32_f16(pa1, vb1, oacc, 0, 0, 0);
    }

    // AO write (f16, merged-head): rows rb*32 + rb2*16 + 4g+q, col h*64 + dd
    {
        const int b = bh >> 4, h = bh & 15;
#pragma unroll
        for (int qq = 0; qq < 4; ++qq) {
            int l = rb * 32 + rb2 * 16 + 4 * g + qq;
            AO[((size_t)b * LSEQ + l) * D_MODEL + h * 64 + dd] = (f16)oacc[qq];
        }
    }
}

extern "C" void kernel_launch(void* const* d_in, const int* in_sizes, int n_in,
                              void* d_out, int out_size, void* d_ws, size_t ws_size,
                              hipStream_t stream) {
    const float* q  = (const float*)d_in[0];
    const float* k  = (const float*)d_in[1];
    const float* v  = (const float*)d_in[2];
    const float* Wq = (const float*)d_in[3];
    const float* bq = (const float*)d_in[4];
    const float* Wk = (const float*)d_in[5];
    const float* bk = (const float*)d_in[6];
    const float* Wv = (const float*)d_in[7];
    const float* bv = (const float*)d_in[8];
    const float* Wo = (const float*)d_in[9];
    const float* bo = (const float*)d_in[10];
    const float* lq = (const float*)d_in[11];
    const float* lk = (const float*)d_in[12];
    const float* lv = (const float*)d_in[13];

    float* out   = (float*)d_out;                          // [4,1024,1024] fp32
    float* attnW = out + (size_t)BSZ * LSEQ * D_MODEL;     // [4,16,1024,1024] fp32

    f16* ws16 = (f16*)d_ws;
    const size_t HSZ = (size_t)BH * LSEQ * HD;             // 4194304
    f16* Qs   = ws16;
    f16* Kh   = ws16 + HSZ;
    f16* Vh   = ws16 + 2 * HSZ;
    f16* Vt   = ws16 + 3 * HSZ;        // [bh][d][l]
    f16* AO   = ws16 + 4 * HSZ;        // [b][l][D]
    f16* W16q = ws16 + 5 * HSZ;
    f16* W16k = W16q + 1048576;
    f16* W16v = W16k + 1048576;
    f16* W16o = W16v + 1048576;
    float* lam = (float*)(W16o + 1048576);

    cvt4_kernel<<<dim3(512, 4), 256, 0, stream>>>(Wq, Wk, Wv, Wo, W16q, W16k, W16v, W16o,
                                                  lq, lk, lv, lam);

    gemm_qkv_kernel<<<dim3(8, 32, 3), 256, 0, stream>>>(
        q, k, v, W16q, W16k, W16v, bq, bk, bv, lam, Qs, Kh, Vh, Vt);

    attn_kernel<<<2048, 512, 0, stream>>>(Qs, Kh, Vh, Vt, lam, attnW, AO);

    gemm_ao_kernel<<<dim3(8, 32), 256, 0, stream>>>(AO, W16o, bo, out);
}

// Round 11
// 248.706 us; speedup vs baseline: 1.3259x; 1.3259x over previous
//
#include <hip/hip_runtime.h>
#include <math.h>

#define D_MODEL 1024
#define NHEADS  16
#define HD      64
#define BSZ     4
#define LSEQ    1024
#define BH      64

typedef _Float16 f16;
typedef _Float16 f16x8 __attribute__((ext_vector_type(8)));
typedef _Float16 f16x4 __attribute__((ext_vector_type(4)));
typedef float    f32x4 __attribute__((ext_vector_type(4)));

typedef const __attribute__((address_space(1))) void* gp1_t;
typedef __attribute__((address_space(3))) void* lp3_t;

__device__ __forceinline__ void gload_lds16(const void* g, void* l) {
    __builtin_amdgcn_global_load_lds((gp1_t)g, (lp3_t)l, 16, 0, 0);
}

// ---------------- weights cvt (4x) + lambda scalars folded in ----------------
__global__ __launch_bounds__(256) void cvt4_kernel(
    const float* __restrict__ s0, const float* __restrict__ s1,
    const float* __restrict__ s2, const float* __restrict__ s3,
    f16* __restrict__ d0, f16* __restrict__ d1, f16* __restrict__ d2, f16* __restrict__ d3,
    const float* __restrict__ lq, const float* __restrict__ lk,
    const float* __restrict__ lv, float* __restrict__ lam) {
    int which = blockIdx.y;
    const float* src = which == 0 ? s0 : which == 1 ? s1 : which == 2 ? s2 : s3;
    f16* dst = which == 0 ? d0 : which == 1 ? d1 : which == 2 ? d2 : d3;
    int i = blockIdx.x * blockDim.x + threadIdx.x;
    if (i < 131072) {
        float4 a = *(const float4*)(src + (size_t)i * 8);
        float4 b = *(const float4*)(src + (size_t)i * 8 + 4);
        f16x8 h;
        h[0]=(f16)a.x; h[1]=(f16)a.y; h[2]=(f16)a.z; h[3]=(f16)a.w;
        h[4]=(f16)b.x; h[5]=(f16)b.y; h[6]=(f16)b.z; h[7]=(f16)b.w;
        *(f16x8*)(dst + (size_t)i * 8) = h;
    }
    if (blockIdx.x == 0 && blockIdx.y == 0 && threadIdx.x < 64) {
        int t = threadIdx.x;
        float pc = lk[t] * lv[t];
        float ps = lq[t] * lk[t];
#pragma unroll
        for (int o = 32; o > 0; o >>= 1) {
            pc += __shfl_down(pc, o, 64);
            ps += __shfl_down(ps, o, 64);
        }
        if (t == 0) {
            float lamC = expf(pc), lamS = expf(ps);
            lam[0] = lamC; lam[1] = lamS;
            lam[2] = lamC / lamS;        // alpha: pre-scales Q
            lam[3] = 0.125f * lamS;      // gamma: post-scales MFMA scores
        }
    }
}

// ---------------- merged QKV projection: Y = X @ W^T + bias (f16 MFMA, dbuf) ----------------
// z=0: Qs (head-split f16, *alpha)   z=1: Kh   z=2: Vh + Vt (transposed copy)
__global__ __launch_bounds__(256, 2) void gemm_qkv_kernel(
    const float* __restrict__ q, const float* __restrict__ k, const float* __restrict__ v,
    const f16* __restrict__ Wq, const f16* __restrict__ Wk, const f16* __restrict__ Wv,
    const float* __restrict__ bq, const float* __restrict__ bk, const float* __restrict__ bv,
    const float* __restrict__ lam,
    f16* __restrict__ Qs, f16* __restrict__ Kh, f16* __restrict__ Vh, f16* __restrict__ Vt)
{
    __shared__ f16 At[2][128 * 64];   // pitch 128B, XOR-swizzled ((row&7)<<4)
    __shared__ f16 Bt[2][128 * 64];

    const int z = blockIdx.z;
    const float* X    = (z == 0) ? q  : (z == 1) ? k  : v;
    const f16*   W    = (z == 0) ? Wq : (z == 1) ? Wk : Wv;
    const float* bias = (z == 0) ? bq : (z == 1) ? bk : bv;

    const int t = threadIdx.x;
    const int lane = t & 63, w = t >> 6;
    const int g = lane >> 4, ln = lane & 15;
    const int wr = w >> 1, wc = w & 1;
    const int n0 = blockIdx.x * 128, m0 = blockIdx.y * 128;
    const int ar = t >> 1, ak = (t & 1) * 32;   // fp32 A staging: row, col-base

    f32x4 acc[4][4];
#pragma unroll
    for (int mi = 0; mi < 4; ++mi)
#pragma unroll
        for (int ni = 0; ni < 4; ++ni)
            acc[mi][ni] = (f32x4){0.f, 0.f, 0.f, 0.f};

    // prologue: stage tile 0
    {
        const float* src = X + (size_t)(m0 + ar) * 1024 + ak;
#pragma unroll
        for (int c = 0; c < 4; ++c) {
            float4 f0 = ((const float4*)src)[c * 2];
            float4 f1 = ((const float4*)src)[c * 2 + 1];
            f16x8 hv;
            hv[0]=(f16)f0.x; hv[1]=(f16)f0.y; hv[2]=(f16)f0.z; hv[3]=(f16)f0.w;
            hv[4]=(f16)f1.x; hv[5]=(f16)f1.y; hv[6]=(f16)f1.z; hv[7]=(f16)f1.w;
            int kb = (ak + c * 8) * 2;
            *(f16x8*)((char*)At[0] + ar * 128 + (kb ^ ((ar & 7) << 4))) = hv;
        }
#pragma unroll
        for (int i = 0; i < 4; ++i) {
            int o = t * 16 + i * 4096;
            int r = o >> 7, kb = (o & 127) ^ ((r & 7) << 4);
            gload_lds16(W + (size_t)(n0 + r) * 1024 + (kb >> 1), (char*)Bt[0] + o);
        }
    }
    __syncthreads();

    int cur = 0;
    for (int kt = 0; kt < 16; ++kt) {
        float4 pre[8];
        if (kt < 15) {
            const float* src = X + (size_t)(m0 + ar) * 1024 + (kt + 1) * 64 + ak;
#pragma unroll
            for (int c = 0; c < 8; ++c) pre[c] = ((const float4*)src)[c];
#pragma unroll
            for (int i = 0; i < 4; ++i) {
                int o = t * 16 + i * 4096;
                int r = o >> 7, kb = (o & 127) ^ ((r & 7) << 4);
                gload_lds16(W + (size_t)(n0 + r) * 1024 + (kt + 1) * 64 + (kb >> 1),
                            (char*)Bt[cur ^ 1] + o);
            }
        }
#pragma unroll
        for (int ks = 0; ks < 2; ++ks) {
            f16x8 af[4], bf[4];
#pragma unroll
            for (int mi = 0; mi < 4; ++mi) {
                int r = wr * 64 + mi * 16 + ln;
                af[mi] = *(const f16x8*)((const char*)At[cur] + r * 128 + ((ks * 64 + g * 16) ^ ((r & 7) << 4)));
            }
#pragma unroll
            for (int ni = 0; ni < 4; ++ni) {
                int r = wc * 64 + ni * 16 + ln;
                bf[ni] = *(const f16x8*)((const char*)Bt[cur] + r * 128 + ((ks * 64 + g * 16) ^ ((r & 7) << 4)));
            }
#pragma unroll
            for (int mi = 0; mi < 4; ++mi)
#pragma unroll
                for (int ni = 0; ni < 4; ++ni)
                    acc[mi][ni] = __builtin_amdgcn_mfma_f32_16x16x32_f16(af[mi], bf[ni], acc[mi][ni], 0, 0, 0);
        }
        if (kt < 15) {
#pragma unroll
            for (int c = 0; c < 4; ++c) {
                float4 f0 = pre[c * 2], f1 = pre[c * 2 + 1];
                f16x8 hv;
                hv[0]=(f16)f0.x; hv[1]=(f16)f0.y; hv[2]=(f16)f0.z; hv[3]=(f16)f0.w;
                hv[4]=(f16)f1.x; hv[5]=(f16)f1.y; hv[6]=(f16)f1.z; hv[7]=(f16)f1.w;
                int kb = (ak + c * 8) * 2;
                *(f16x8*)((char*)At[cur ^ 1] + ar * 128 + (kb ^ ((ar & 7) << 4))) = hv;
            }
        }
        __syncthreads();
        cur ^= 1;
    }

    const float alpha = (z == 0) ? lam[2] : 1.0f;
    f16* Y = (z == 0) ? Qs : (z == 1) ? Kh : Vh;
#pragma unroll
    for (int mi = 0; mi < 4; ++mi) {
#pragma unroll
        for (int ni = 0; ni < 4; ++ni) {
            int n = n0 + wc * 64 + ni * 16 + ln;
            int h = n >> 6, d = n & 63;
            float bn = bias[n];
            int mrow0 = m0 + wr * 64 + mi * 16 + 4 * g;
            int b = mrow0 >> 10, l0 = mrow0 & 1023;
            f16x4 tv;
#pragma unroll
            for (int qq = 0; qq < 4; ++qq) {
                float val = (acc[mi][ni][qq] + bn) * alpha;
                f16 hq = (f16)val;
                tv[qq] = hq;
                Y[(((size_t)(b * NHEADS + h)) * LSEQ + l0 + qq) * HD + d] = hq;
            }
            if (z == 2)
                *(f16x4*)(Vt + ((size_t)(b * NHEADS + h) * HD + d) * LSEQ + l0) = tv;
        }
    }
}

// ---------------- AO GEMM: out = AO @ Wo^T + bo (f16 A, fp32 out, dbuf) ----------------
__global__ __launch_bounds__(256, 2) void gemm_ao_kernel(
    const f16* __restrict__ A16, const f16* __restrict__ W16,
    const float* __restrict__ bias, float* __restrict__ out)
{
    __shared__ f16 At[2][128 * 64];
    __shared__ f16 Bt[2][128 * 64];

    const int t = threadIdx.x;
    const int lane = t & 63, w = t >> 6;
    const int g = lane >> 4, ln = lane & 15;
    const int wr = w >> 1, wc = w & 1;
    const int n0 = blockIdx.x * 128, m0 = blockIdx.y * 128;

    f32x4 acc[4][4];
#pragma unroll
    for (int mi = 0; mi < 4; ++mi)
#pragma unroll
        for (int ni = 0; ni < 4; ++ni)
            acc[mi][ni] = (f32x4){0.f, 0.f, 0.f, 0.f};

#pragma unroll
    for (int i = 0; i < 4; ++i) {
        int o = t * 16 + i * 4096;
        int r = o >> 7, kb = (o & 127) ^ ((r & 7) << 4);
        gload_lds16(A16 + (size_t)(m0 + r) * 1024 + (kb >> 1), (char*)At[0] + o);
        gload_lds16(W16 + (size_t)(n0 + r) * 1024 + (kb >> 1), (char*)Bt[0] + o);
    }
    __syncthreads();

    int cur = 0;
    for (int kt = 0; kt < 16; ++kt) {
        if (kt < 15) {
#pragma unroll
            for (int i = 0; i < 4; ++i) {
                int o = t * 16 + i * 4096;
                int r = o >> 7, kb = (o & 127) ^ ((r & 7) << 4);
                gload_lds16(A16 + (size_t)(m0 + r) * 1024 + (kt + 1) * 64 + (kb >> 1), (char*)At[cur ^ 1] + o);
                gload_lds16(W16 + (size_t)(n0 + r) * 1024 + (kt + 1) * 64 + (kb >> 1), (char*)Bt[cur ^ 1] + o);
            }
        }
#pragma unroll
        for (int ks = 0; ks < 2; ++ks) {
            f16x8 af[4], bf[4];
#pragma unroll
            for (int mi = 0; mi < 4; ++mi) {
                int r = wr * 64 + mi * 16 + ln;
                af[mi] = *(const f16x8*)((const char*)At[cur] + r * 128 + ((ks * 64 + g * 16) ^ ((r & 7) << 4)));
            }
#pragma unroll
            for (int ni = 0; ni < 4; ++ni) {
                int r = wc * 64 + ni * 16 + ln;
                bf[ni] = *(const f16x8*)((const char*)Bt[cur] + r * 128 + ((ks * 64 + g * 16) ^ ((r & 7) << 4)));
            }
#pragma unroll
            for (int mi = 0; mi < 4; ++mi)
#pragma unroll
                for (int ni = 0; ni < 4; ++ni)
                    acc[mi][ni] = __builtin_amdgcn_mfma_f32_16x16x32_f16(af[mi], bf[ni], acc[mi][ni], 0, 0, 0);
        }
        __syncthreads();
        cur ^= 1;
    }

#pragma unroll
    for (int mi = 0; mi < 4; ++mi)
#pragma unroll
        for (int ni = 0; ni < 4; ++ni) {
            int n = n0 + wc * 64 + ni * 16 + ln;
            float bn = bias[n];
#pragma unroll
            for (int qq = 0; qq < 4; ++qq) {
                int m = m0 + wr * 64 + mi * 16 + 4 * g + qq;
                out[(size_t)m * 1024 + n] = acc[mi][ni][qq] + bn;
            }
        }
}

// ---------------- single-pass fused attention, LDS-staged phase 1 ----------------
// 32 q-rows/block, 512 threads (8 waves), grid 2048. exp(scores) in f16 regs.
// Phase 1: K|V tile staged ONCE per block via global_load_lds (dense 1KB/instr)
//          into a 2x16KB dbuf carved from WsAll; fragments via swizzled LDS
//          reads; 1 barrier/tile. (Replaces per-lane global gathers: 16x fewer
//          L2 transactions.)
// Phase 2a: normalize -> WsAll fill. ONE barrier.
// Phase 2b: lane-coalesced plain attnW stream (1KB/instr dense).
// Phase 2c: PV MFMA over WsAll.
__global__ __launch_bounds__(512, 4) void attn_kernel(
    const f16* __restrict__ Qs, const f16* __restrict__ Kh, const f16* __restrict__ Vh,
    const f16* __restrict__ Vt, const float* __restrict__ lam,
    float* __restrict__ attnW, f16* __restrict__ AO)
{
    __shared__ __align__(16) f16 WsAll[16][2048];   // 64 KB; first 32 KB double as phase-1 KV dbuf
    __shared__ float rsum[4][2][16];                // [ci][ri][ln]

    const int t = threadIdx.x;
    const int lane = t & 63, w = t >> 6;
    const int g = lane >> 4, ln = lane & 15;
    const int ci = w & 3, ri = w >> 2;          // phase-1 wave role

    const int bid = blockIdx.x;                 // 0..2047
    const int wg = (bid & 7) * 256 + (bid >> 3);// XCD-contiguous swizzle (8 XCDs)
    const int bh = wg >> 5, rb = wg & 31;
    const size_t hbase = (size_t)bh * LSEQ * HD;
    const float gamma = lam[3];

    char* kv = (char*)WsAll;                    // dbuf: kv + p*16384

    // Q-side B-frags: row = rb*32 + ri*16 + ln, [alpha*Q | K] along k
    f16x8 qf[4];
    {
        const int qrow = rb * 32 + ri * 16 + ln;
        const f16* qp = Qs + hbase + (size_t)qrow * HD;
        const f16* kp = Kh + hbase + (size_t)qrow * HD;
        qf[0] = *(const f16x8*)(qp + g * 8);
        qf[1] = *(const f16x8*)(qp + 32 + g * 8);
        qf[2] = *(const f16x8*)(kp + g * 8);
        qf[3] = *(const f16x8*)(kp + 32 + g * 8);
    }

    // stage tile 0 -> buf 0  (rows = kv cols c, [K(128B)|V(128B)] per row, swizzled src)
#pragma unroll
    for (int i = 0; i < 2; ++i) {
        int o = t * 16 + i * 8192;
        int r = o >> 8, kb = (o & 255) ^ ((r & 7) << 4);
        const f16* src = (kb < 128) ? (Kh + hbase + (size_t)r * HD + (kb >> 1))
                                    : (Vh + hbase + (size_t)r * HD + ((kb - 128) >> 1));
        gload_lds16(src, kv + o);
    }
    __syncthreads();

    // ---------- phase 1: staged scores + exp + row sums (1 barrier/tile) ----------
    float lsum = 0.f;
    f16x4 sregh[16];
    const int cc = ci * 16 + ln;                // this lane's key-column
    const int csw = (cc & 7) << 4;
#pragma unroll
    for (int tt = 0; tt < 16; ++tt) {
        const int cur = tt & 1;
        if (tt < 15) {   // prefetch next tile into other buffer
            const int c0 = (tt + 1) * 64;
#pragma unroll
            for (int i = 0; i < 2; ++i) {
                int o = t * 16 + i * 8192;
                int r = o >> 8, kb = (o & 255) ^ ((r & 7) << 4);
                const f16* src = (kb < 128) ? (Kh + hbase + (size_t)(c0 + r) * HD + (kb >> 1))
                                            : (Vh + hbase + (size_t)(c0 + r) * HD + ((kb - 128) >> 1));
                gload_lds16(src, kv + (cur ^ 1) * 16384 + o);
            }
        }
        const char* crow = kv + cur * 16384 + cc * 256;
        f32x4 acc = (f32x4){0.f, 0.f, 0.f, 0.f};
#pragma unroll
        for (int ks = 0; ks < 4; ++ks) {
            f16x8 af = *(const f16x8*)(crow + ((ks * 64 + g * 16) ^ csw));
            acc = __builtin_amdgcn_mfma_f32_16x16x32_f16(af, qf[ks], acc, 0, 0, 0);
        }
        float e0 = __expf(acc[0] * gamma);
        float e1 = __expf(acc[1] * gamma);
        float e2 = __expf(acc[2] * gamma);
        float e3 = __expf(acc[3] * gamma);
        lsum += (e0 + e1) + (e2 + e3);
        f16x4 eh;
        eh[0] = (f16)e0; eh[1] = (f16)e1; eh[2] = (f16)e2; eh[3] = (f16)e3;
        sregh[tt] = eh;
        __syncthreads();   // next tile staged AND this buffer consumed
    }
    lsum += __shfl_xor(lsum, 16, 64);
    lsum += __shfl_xor(lsum, 32, 64);
    if (g == 0) rsum[ci][ri][ln] = lsum;
    __syncthreads();
    const float il = 1.0f / ((rsum[0][ri][ln] + rsum[1][ri][ln]) +
                             (rsum[2][ri][ln] + rsum[3][ri][ln]));

    // ---------- phase 2a: normalized f16 weights -> WsAll ----------
    const int r1 = ri * 16 + ln;                           // this wave's score row
    const int wsw = (32 * ci + 8 * g) ^ ((r1 & 7) << 4);   // Ws write byte offset in row
#pragma unroll
    for (int tt = 0; tt < 16; ++tt) {
        f16x4 eh = sregh[tt];
        f16x4 wh;
        wh[0] = (f16)((float)eh[0] * il);
        wh[1] = (f16)((float)eh[1] * il);
        wh[2] = (f16)((float)eh[2] * il);
        wh[3] = (f16)((float)eh[3] * il);
        *(f16x4*)((char*)WsAll[tt] + r1 * 128 + wsw) = wh;
    }
    __syncthreads();   // WsAll visible to all waves

    // ---------- phase 2b: lane-coalesced attnW stream (plain stores) ----------
    {
#pragma unroll
        for (int rr = 0; rr < 4; ++rr) {
            const int row = w * 4 + rr;
            const int swz = row & 7;
            const int lds_off = row * 128 + ((((lane & 15) * 8)) ^ (swz << 4));
            float* gdst = attnW + ((size_t)bh * LSEQ + rb * 32 + row) * LSEQ + lane * 4;
#pragma unroll
            for (int qu = 0; qu < 4; ++qu) {
                const int s = qu * 4 + (lane >> 4);
                f16x4 hv = *(const f16x4*)((const char*)WsAll[s] + lds_off);
                f32x4 o;
                o[0] = (float)hv[0]; o[1] = (float)hv[1];
                o[2] = (float)hv[2]; o[3] = (float)hv[3];
                *(f32x4*)(gdst + qu * 256) = o;
            }
        }
    }

    // ---------- phase 2c: PV over WsAll (overlaps store drain) ----------
    const int dj = w & 3, rb2 = w >> 2;         // phase-2 wave role
    const int r2 = rb2 * 16 + ln;               // pa row
    const int dd = dj * 16 + ln;                // Vt row
    const f16* vtrow = Vt + (size_t)bh * HD * LSEQ + (size_t)dd * LSEQ;
    const int psw0 = (16 * g) ^ ((r2 & 7) << 4);           // pa ks=0 byte offset
    const int psw1 = (64 + 16 * g) ^ ((r2 & 7) << 4);      // pa ks=1
    f32x4 oacc = (f32x4){0.f, 0.f, 0.f, 0.f};

#pragma unroll
    for (int tt = 0; tt < 16; ++tt) {
        f16x8 vb0 = *(const f16x8*)(vtrow + tt * 64 + g * 8);
        f16x8 vb1 = *(const f16x8*)(vtrow + tt * 64 + 32 + g * 8);
        f16x8 pa0 = *(const f16x8*)((const char*)WsAll[tt] + r2 * 128 + psw0);
        f16x8 pa1 = *(const f16x8*)((const char*)WsAll[tt] + r2 * 128 + psw1);
        oacc = __builtin_amdgcn_mfma_f32_16x16x32_f16(pa0, vb0, oacc, 0, 0, 0);
        oacc = __builtin_amdgcn_mfma_f32_16x16x32_f16(pa1, vb1, oacc, 0, 0, 0);
    }

    // AO write (f16, merged-head): rows rb*32 + rb2*16 + 4g+q, col h*64 + dd
    {
        const int b = bh >> 4, h = bh & 15;
#pragma unroll
        for (int qq = 0; qq < 4; ++qq) {
            int l = rb * 32 + rb2 * 16 + 4 * g + qq;
            AO[((size_t)b * LSEQ + l) * D_MODEL + h * 64 + dd] = (f16)oacc[qq];
        }
    }
}

extern "C" void kernel_launch(void* const* d_in, const int* in_sizes, int n_in,
                              void* d_out, int out_size, void* d_ws, size_t ws_size,
                              hipStream_t stream) {
    const float* q  = (const float*)d_in[0];
    const float* k  = (const float*)d_in[1];
    const float* v  = (const float*)d_in[2];
    const float* Wq = (const float*)d_in[3];
    const float* bq = (const float*)d_in[4];
    const float* Wk = (const float*)d_in[5];
    const float* bk = (const float*)d_in[6];
    const float* Wv = (const float*)d_in[7];
    const float* bv = (const float*)d_in[8];
    const float* Wo = (const float*)d_in[9];
    const float* bo = (const float*)d_in[10];
    const float* lq = (const float*)d_in[11];
    const float* lk = (const float*)d_in[12];
    const float* lv = (const float*)d_in[13];

    float* out   = (float*)d_out;                          // [4,1024,1024] fp32
    float* attnW = out + (size_t)BSZ * LSEQ * D_MODEL;     // [4,16,1024,1024] fp32

    f16* ws16 = (f16*)d_ws;
    const size_t HSZ = (size_t)BH * LSEQ * HD;             // 4194304
    f16* Qs   = ws16;
    f16* Kh   = ws16 + HSZ;
    f16* Vh   = ws16 + 2 * HSZ;
    f16* Vt   = ws16 + 3 * HSZ;        // [bh][d][l]
    f16* AO   = ws16 + 4 * HSZ;        // [b][l][D]
    f16* W16q = ws16 + 5 * HSZ;
    f16* W16k = W16q + 1048576;
    f16* W16v = W16k + 1048576;
    f16* W16o = W16v + 1048576;
    float* lam = (float*)(W16o + 1048576);

    cvt4_kernel<<<dim3(512, 4), 256, 0, stream>>>(Wq, Wk, Wv, Wo, W16q, W16k, W16v, W16o,
                                                  lq, lk, lv, lam);

    gemm_qkv_kernel<<<dim3(8, 32, 3), 256, 0, stream>>>(
        q, k, v, W16q, W16k, W16v, bq, bk, bv, lam, Qs, Kh, Vh, Vt);

    attn_kernel<<<2048, 512, 0, stream>>>(Qs, Kh, Vh, Vt, lam, attnW, AO);

    gemm_ao_kernel<<<dim3(8, 32), 256, 0, stream>>>(AO, W16o, bo, out);
}